// Round 1
// baseline (74.942 us; speedup 1.0000x reference)
//
#include <hip/hip_runtime.h>

// Quantum circuit: NQ=8 qubits, NL=3 layers, B=65536 samples, DIM=256 amps.
// Layout: 4 lanes per sample; lane `sub` (tid&3) holds amps idx = i*4+sub,
// i = 0..63 in registers (re[64], im[64]).
// Wire q <-> idx bit (7-q). Wires 0..5 -> bits of i (register-local pairs);
// wires 6,7 -> bits of sub (cross-lane via DPP quad_perm xor2/xor1).

template <int CTRL>
__device__ __forceinline__ float dppf(float x) {
    return __int_as_float(
        __builtin_amdgcn_mov_dpp(__float_as_int(x), CTRL, 0xF, 0xF, true));
}

__global__ __launch_bounds__(256, 2)
void qsim_kernel(const float* __restrict__ w, const float* __restrict__ z1,
                 const float* __restrict__ z2, float* __restrict__ out,
                 int nsamp) {
    __shared__ float2 s_diag[3][256];  // RZZ diagonal per layer: exp(-0.5i*ang)
    __shared__ float2 s_cs[3][8];      // (cos, sin) of weights[l][q]/2

    const int t = threadIdx.x;

    // Build LDS tables (shared by all 64 samples of this block).
    #pragma unroll
    for (int l = 0; l < 3; ++l) {
        float ang = 0.f;
        #pragma unroll
        for (int i = 0; i < 7; ++i) {
            // zz_i(idx) = +1 if bits (7-i),(6-i) equal else -1
            float zz = (((t >> (7 - i)) ^ (t >> (6 - i))) & 1) ? -1.f : 1.f;
            ang = fmaf(w[l * 15 + 8 + i], zz, ang);
        }
        float sv, cv;
        __sincosf(0.5f * ang, &sv, &cv);
        s_diag[l][t] = make_float2(cv, -sv);   // exp(-0.5 i ang)
    }
    if (t < 24) {
        int l = t >> 3, q = t & 7;
        float a = 0.5f * w[l * 15 + q];
        s_cs[l][q] = make_float2(__cosf(a), __sinf(a));
    }
    __syncthreads();

    const int gtid = blockIdx.x * 256 + t;
    const int s = gtid >> 2;
    const int sub = t & 3;
    if (s >= nsamp) return;

    // ---- analytic initial product state: amp[idx] = v0^8 * t^popcount(idx)
    // v0 = cos(a1/2) e^{-i a2/2}, v1 = sin(a1/2) e^{+i a2/2},
    // t = v1/v0 = tan(a1/2) * (cos a2 + i sin a2);  a1=asin z1, a2=asin z2.
    const float z1v = z1[s], z2v = z2[s];
    const float u1 = sqrtf(fmaxf(0.f, 1.f - z1v * z1v));  // cos a1
    const float u2 = sqrtf(fmaxf(0.f, 1.f - z2v * z2v));  // cos a2
    const float q1 = 0.5f * (1.f + u1);                    // cos^2(a1/2)
    const float c1 = sqrtf(q1);
    const float s1 = copysignf(sqrtf(fmaxf(0.f, 0.5f * (1.f - u1))), z1v);
    const float tn = s1 / c1;          // tan(a1/2), |tn|<=1
    const float tr = tn * u2, ti = tn * z2v;
    float c1_8 = q1 * q1; c1_8 *= c1_8;              // cos^8(a1/2)
    const float c2a = 1.f - 2.f * z2v * z2v;         // cos 2a2
    const float s2a = 2.f * u2 * z2v;                // sin 2a2
    const float c4a = 1.f - 2.f * s2a * s2a;         // cos 4a2
    const float s4a = 2.f * s2a * c2a;               // sin 4a2
    const float v8r = c1_8 * c4a, v8i = -c1_8 * s4a; // v0^8

    // W[m] = v0^8 * t^(popcount(sub)+m); amp[i*4+sub] = W[popcount(i)]
    const float t2r = tr * tr - ti * ti, t2i = 2.f * tr * ti;
    const int psub = __popc(sub);  // 0..2
    const float tpr = (psub == 0) ? 1.f : ((psub == 1) ? tr : t2r);
    const float tpi = (psub == 0) ? 0.f : ((psub == 1) ? ti : t2i);
    float Wr[7], Wi[7];
    Wr[0] = v8r * tpr - v8i * tpi;
    Wi[0] = v8r * tpi + v8i * tpr;
    #pragma unroll
    for (int m = 0; m < 6; ++m) {
        Wr[m + 1] = Wr[m] * tr - Wi[m] * ti;
        Wi[m + 1] = Wr[m] * ti + Wi[m] * tr;
    }

    float re[64], im[64];
    #pragma unroll
    for (int i = 0; i < 64; ++i) {
        re[i] = Wr[__builtin_popcount(i)];
        im[i] = Wi[__builtin_popcount(i)];
    }

    // ---- circuit layers (rolled loop: keep code size small)
    #pragma unroll 1
    for (int l = 0; l < 3; ++l) {
        // RY on wires 0..5: register-local pairs on bit b = 5-q of i
        #pragma unroll
        for (int q = 0; q < 6; ++q) {
            const int b = 5 - q;
            const float2 cs = s_cs[l][q];
            const float cq = cs.x, sq = cs.y;
            #pragma unroll
            for (int h = 0; h < 32; ++h) {
                const int lm = (1 << b) - 1;
                const int i0 = ((h & ~lm) << 1) | (h & lm);
                const int i1 = i0 | (1 << b);
                float a0 = re[i0], a1 = re[i1];
                re[i0] = cq * a0 - sq * a1;
                re[i1] = sq * a0 + cq * a1;
                a0 = im[i0]; a1 = im[i1];
                im[i0] = cq * a0 - sq * a1;
                im[i1] = sq * a0 + cq * a1;
            }
        }
        // RY wire 6: idx bit1 = sub bit1 -> quad_perm xor2 (0x4E)
        {
            const float2 cs = s_cs[l][6];
            const float cq = cs.x;
            const float se = (sub & 2) ? cs.y : -cs.y;
            #pragma unroll
            for (int i = 0; i < 64; ++i) {
                const float pr = dppf<0x4E>(re[i]);
                const float pi = dppf<0x4E>(im[i]);
                re[i] = fmaf(cq, re[i], se * pr);
                im[i] = fmaf(cq, im[i], se * pi);
            }
        }
        // RY wire 7: idx bit0 = sub bit0 -> quad_perm xor1 (0xB1)
        {
            const float2 cs = s_cs[l][7];
            const float cq = cs.x;
            const float se = (sub & 1) ? cs.y : -cs.y;
            #pragma unroll
            for (int i = 0; i < 64; ++i) {
                const float pr = dppf<0xB1>(re[i]);
                const float pi = dppf<0xB1>(im[i]);
                re[i] = fmaf(cq, re[i], se * pr);
                im[i] = fmaf(cq, im[i], se * pi);
            }
        }
        // fused CNOT-RZ-CNOT block: diagonal phase multiply
        #pragma unroll
        for (int i = 0; i < 64; ++i) {
            const float2 d = s_diag[l][(i << 2) | sub];
            const float rr = re[i], ii = im[i];
            re[i] = rr * d.x - ii * d.y;
            im[i] = fmaf(rr, d.y, ii * d.x);
        }
    }

    // ---- probabilities + signed sums
    #pragma unroll
    for (int i = 0; i < 64; ++i) re[i] = fmaf(re[i], re[i], im[i] * im[i]);

    // wires 0..5: i-bit (5-q); peel MSB-first, accumulating signed diff sums
    float zq[6];
    #pragma unroll
    for (int wq = 0; wq < 6; ++wq) {
        const int half = 32 >> wq;
        float d = 0.f;
        #pragma unroll
        for (int j = 0; j < half; ++j) {
            d += re[j] - re[j + half];
            re[j] += re[j + half];
        }
        zq[wq] = d;
    }
    const float T = re[0];  // per-lane total probability mass

    float S[8];
    #pragma unroll
    for (int wq = 0; wq < 6; ++wq) S[wq] = zq[wq];
    S[6] = (sub & 2) ? -T : T;
    S[7] = (sub & 1) ? -T : T;

    // quad (4-lane) butterfly sums
    #pragma unroll
    for (int k = 0; k < 8; ++k) {
        S[k] += dppf<0xB1>(S[k]);
        S[k] += dppf<0x4E>(S[k]);
    }

    // lane sub writes outputs (2*sub, 2*sub+1) -> fully coalesced float2
    float oa, ob;
    if (sub == 0)      { oa = S[0]; ob = S[1]; }
    else if (sub == 1) { oa = S[2]; ob = S[3]; }
    else if (sub == 2) { oa = S[4]; ob = S[5]; }
    else               { oa = S[6]; ob = S[7]; }
    float2* op = (float2*)(out + (size_t)s * 8 + sub * 2);
    *op = make_float2(oa, ob);
}

extern "C" void kernel_launch(void* const* d_in, const int* in_sizes, int n_in,
                              void* d_out, int out_size, void* d_ws,
                              size_t ws_size, hipStream_t stream) {
    const float* w  = (const float*)d_in[0];   // (3, 15) f32
    const float* z1 = (const float*)d_in[1];   // (B,)   f32
    const float* z2 = (const float*)d_in[2];   // (B,)   f32
    float* out = (float*)d_out;                // (B, 8) f32

    const int n = in_sizes[1];
    const int blocks = (n * 4 + 255) / 256;
    qsim_kernel<<<blocks, 256, 0, stream>>>(w, z1, z2, out, n);
}

// Round 2
// 45.499 us; speedup vs baseline: 1.6471x; 1.6471x over previous
//
#include <hip/hip_runtime.h>

// Quantum circuit: NQ=8 qubits, NL=3 layers, B=65536 samples, DIM=256 amps.
// Layout: 4 lanes per sample; lane `sub` (tid&3) holds amps idx = i*4+sub,
// i = 0..63 in registers as v2f amp[64] = (re, im) pairs -> v_pk_* packed ops.
// Wire q <-> idx bit (7-q). Wires 0..5 -> bits of i (register-local pairs);
// wires 6,7 -> bits of sub (cross-lane via DPP quad_perm xor2/xor1).
// Last layer's RZZ diagonal is a pure phase -> skipped (|amp|^2 invariant).

typedef float v2f __attribute__((ext_vector_type(2)));

__device__ __forceinline__ v2f splat(float x) { v2f r; r.x = x; r.y = x; return r; }

template <int CTRL>
__device__ __forceinline__ float dppf(float x) {
    return __int_as_float(
        __builtin_amdgcn_mov_dpp(__float_as_int(x), CTRL, 0xF, 0xF, true));
}

__global__ __launch_bounds__(256, 1)
void qsim_kernel(const float* __restrict__ w, const float* __restrict__ z1,
                 const float* __restrict__ z2, float* __restrict__ out,
                 int nsamp) {
    __shared__ v2f s_diag[2][256];  // RZZ diagonal, layers 0..1: exp(-0.5i*ang)
    __shared__ v2f s_cs[3][8];      // (cos, sin) of weights[l][q]/2

    const int t = threadIdx.x;

    // Build LDS tables (shared by all 64 samples of this block).
    #pragma unroll
    for (int l = 0; l < 2; ++l) {
        float ang = 0.f;
        #pragma unroll
        for (int i = 0; i < 7; ++i) {
            // zz_i(idx) = +1 if bits (7-i),(6-i) equal else -1
            float zz = (((t >> (7 - i)) ^ (t >> (6 - i))) & 1) ? -1.f : 1.f;
            ang = fmaf(w[l * 15 + 8 + i], zz, ang);
        }
        float sv, cv;
        __sincosf(0.5f * ang, &sv, &cv);
        v2f d; d.x = cv; d.y = -sv;        // exp(-0.5 i ang)
        s_diag[l][t] = d;
    }
    if (t < 24) {
        int l = t >> 3, q = t & 7;
        float a = 0.5f * w[l * 15 + q];
        v2f cs; cs.x = __cosf(a); cs.y = __sinf(a);
        s_cs[l][q] = cs;
    }
    __syncthreads();

    const int gtid = blockIdx.x * 256 + t;
    const int s = gtid >> 2;
    const int sub = t & 3;
    if (s >= nsamp) return;

    // ---- analytic initial product state: amp[idx] = v0^8 * t^popcount(idx)
    // v0 = cos(a1/2) e^{-i a2/2}, v1 = sin(a1/2) e^{+i a2/2},
    // t = v1/v0 = tan(a1/2) * (cos a2 + i sin a2);  a1=asin z1, a2=asin z2.
    const float z1v = z1[s], z2v = z2[s];
    const float u1 = sqrtf(fmaxf(0.f, 1.f - z1v * z1v));  // cos a1
    const float u2 = sqrtf(fmaxf(0.f, 1.f - z2v * z2v));  // cos a2
    const float q1 = 0.5f * (1.f + u1);                    // cos^2(a1/2)
    const float c1 = sqrtf(q1);
    const float s1 = copysignf(sqrtf(fmaxf(0.f, 0.5f * (1.f - u1))), z1v);
    const float tn = s1 / c1;          // tan(a1/2), |tn|<=1
    const float tr = tn * u2, ti = tn * z2v;
    float c1_8 = q1 * q1; c1_8 *= c1_8;              // cos^8(a1/2)
    const float c2a = 1.f - 2.f * z2v * z2v;         // cos 2a2
    const float s2a = 2.f * u2 * z2v;                // sin 2a2
    const float c4a = 1.f - 2.f * s2a * s2a;         // cos 4a2
    const float s4a = 2.f * s2a * c2a;               // sin 4a2
    const float v8r = c1_8 * c4a, v8i = -c1_8 * s4a; // v0^8

    // W[m] = v0^8 * t^(popcount(sub)+m); amp[i*4+sub] = W[popcount(i)]
    const float t2r = tr * tr - ti * ti, t2i = 2.f * tr * ti;
    const int psub = __popc(sub);  // 0..2
    const float tpr = (psub == 0) ? 1.f : ((psub == 1) ? tr : t2r);
    const float tpi = (psub == 0) ? 0.f : ((psub == 1) ? ti : t2i);
    v2f W[7];
    W[0].x = v8r * tpr - v8i * tpi;
    W[0].y = v8r * tpi + v8i * tpr;
    #pragma unroll
    for (int m = 0; m < 6; ++m) {
        W[m + 1].x = W[m].x * tr - W[m].y * ti;
        W[m + 1].y = W[m].x * ti + W[m].y * tr;
    }

    v2f amp[64];
    #pragma unroll
    for (int i = 0; i < 64; ++i) amp[i] = W[__builtin_popcount(i)];

    // ---- circuit layers (rolled loop: keep code size small)
    #pragma unroll 1
    for (int l = 0; l < 3; ++l) {
        // RY on wires 0..5: register-local pairs on bit b = 5-q of i.
        // re and im see the SAME real rotation -> packed v_pk_fma_f32 shape.
        #pragma unroll
        for (int q = 0; q < 6; ++q) {
            const int b = 5 - q;
            const v2f cs = s_cs[l][q];
            const v2f cq = splat(cs.x), sq = splat(cs.y);
            #pragma unroll
            for (int h = 0; h < 32; ++h) {
                const int lm = (1 << b) - 1;
                const int i0 = ((h & ~lm) << 1) | (h & lm);
                const int i1 = i0 | (1 << b);
                const v2f a0 = amp[i0], a1 = amp[i1];
                amp[i0] = cq * a0 - sq * a1;
                amp[i1] = sq * a0 + cq * a1;
            }
        }
        // RY wire 6: idx bit1 = sub bit1 -> quad_perm xor2 (0x4E)
        {
            const v2f cs = s_cs[l][6];
            const v2f cq = splat(cs.x);
            const v2f se = splat((sub & 2) ? cs.y : -cs.y);
            #pragma unroll
            for (int i = 0; i < 64; ++i) {
                v2f p; p.x = dppf<0x4E>(amp[i].x); p.y = dppf<0x4E>(amp[i].y);
                amp[i] = cq * amp[i] + se * p;
            }
        }
        // RY wire 7: idx bit0 = sub bit0 -> quad_perm xor1 (0xB1)
        {
            const v2f cs = s_cs[l][7];
            const v2f cq = splat(cs.x);
            const v2f se = splat((sub & 1) ? cs.y : -cs.y);
            #pragma unroll
            for (int i = 0; i < 64; ++i) {
                v2f p; p.x = dppf<0xB1>(amp[i].x); p.y = dppf<0xB1>(amp[i].y);
                amp[i] = cq * amp[i] + se * p;
            }
        }
        // fused CNOT-RZ-CNOT block: diagonal phase multiply.
        // Layer 2's diag is a pure phase before |.|^2 -> skip it.
        if (l < 2) {
            #pragma unroll
            for (int i = 0; i < 64; ++i) {
                const v2f d = s_diag[l][(i << 2) | sub];
                const float rr = amp[i].x, ii = amp[i].y;
                amp[i].x = rr * d.x - ii * d.y;
                amp[i].y = fmaf(rr, d.y, ii * d.x);
            }
        }
    }

    // ---- probabilities + signed sums
    float pr[64];
    #pragma unroll
    for (int i = 0; i < 64; ++i)
        pr[i] = fmaf(amp[i].x, amp[i].x, amp[i].y * amp[i].y);

    // wires 0..5: i-bit (5-q); peel MSB-first, accumulating signed diff sums
    float zq[6];
    #pragma unroll
    for (int wq = 0; wq < 6; ++wq) {
        const int half = 32 >> wq;
        float d = 0.f;
        #pragma unroll
        for (int j = 0; j < half; ++j) {
            d += pr[j] - pr[j + half];
            pr[j] += pr[j + half];
        }
        zq[wq] = d;
    }
    const float T = pr[0];  // per-lane total probability mass

    float S[8];
    #pragma unroll
    for (int wq = 0; wq < 6; ++wq) S[wq] = zq[wq];
    S[6] = (sub & 2) ? -T : T;
    S[7] = (sub & 1) ? -T : T;

    // quad (4-lane) butterfly sums
    #pragma unroll
    for (int k = 0; k < 8; ++k) {
        S[k] += dppf<0xB1>(S[k]);
        S[k] += dppf<0x4E>(S[k]);
    }

    // lane sub writes outputs (2*sub, 2*sub+1) -> fully coalesced float2
    float oa, ob;
    if (sub == 0)      { oa = S[0]; ob = S[1]; }
    else if (sub == 1) { oa = S[2]; ob = S[3]; }
    else if (sub == 2) { oa = S[4]; ob = S[5]; }
    else               { oa = S[6]; ob = S[7]; }
    float2* op = (float2*)(out + (size_t)s * 8 + sub * 2);
    *op = make_float2(oa, ob);
}

extern "C" void kernel_launch(void* const* d_in, const int* in_sizes, int n_in,
                              void* d_out, int out_size, void* d_ws,
                              size_t ws_size, hipStream_t stream) {
    const float* w  = (const float*)d_in[0];   // (3, 15) f32
    const float* z1 = (const float*)d_in[1];   // (B,)   f32
    const float* z2 = (const float*)d_in[2];   // (B,)   f32
    float* out = (float*)d_out;                // (B, 8) f32

    const int n = in_sizes[1];
    const int blocks = (n * 4 + 255) / 256;
    qsim_kernel<<<blocks, 256, 0, stream>>>(w, z1, z2, out, n);
}

// Round 3
// 40.770 us; speedup vs baseline: 1.8382x; 1.1160x over previous
//
#include <hip/hip_runtime.h>

// NQ=8 qubits, NL=3 layers, B=65536. 8 lanes per sample, 32 amps/lane.
// idx bits [7:3] = i (register), [2:0] = sub, with sub mapped to LANE bits
// {3,1,0} (lane bit 2 selects sample within a 16-lane row) so all three
// lane-wires are DPP-reachable: xor8 = row_ror:8, xor2 = 0x4E, xor1 = 0xB1.
// Layer-0 RYs act on a product state -> folded analytically into the init
// (62-cmul product tree). Layer-2 RZZ diag is a pure phase -> skipped.

typedef float v2f __attribute__((ext_vector_type(2)));

__device__ __forceinline__ v2f splat(float x) { v2f r; r.x = x; r.y = x; return r; }

template <int CTRL>
__device__ __forceinline__ float dppf(float x) {
    return __int_as_float(
        __builtin_amdgcn_mov_dpp(__float_as_int(x), CTRL, 0xF, 0xF, true));
}
template <int CTRL>
__device__ __forceinline__ v2f dpp2(v2f a) {
    v2f r; r.x = dppf<CTRL>(a.x); r.y = dppf<CTRL>(a.y); return r;
}

__device__ __forceinline__ v2f cmul(v2f a, v2f b) {
    v2f r;
    r.x = a.x * b.x - a.y * b.y;
    r.y = a.x * b.y + a.y * b.x;
    return r;
}

#define DPP_XOR1 0xB1   // quad_perm [1,0,3,2]
#define DPP_XOR2 0x4E   // quad_perm [2,3,0,1]
#define DPP_XOR8 0x128  // row_ror:8 == lane^8 within a 16-lane row

__global__ __launch_bounds__(256, 2)
void qsim_kernel(const float* __restrict__ w, const float* __restrict__ z1,
                 const float* __restrict__ z2, float* __restrict__ out,
                 int nsamp) {
    __shared__ v2f s_diag[2][256];  // RZZ diagonal, layers 0..1: exp(-0.5i*ang)
    __shared__ v2f s_cs[3][8];      // (cos, sin) of weights[l][q]/2

    const int t = threadIdx.x;

    #pragma unroll
    for (int l = 0; l < 2; ++l) {
        float ang = 0.f;
        #pragma unroll
        for (int i = 0; i < 7; ++i) {
            // zz_i(idx) = +1 if idx bits (7-i),(6-i) equal else -1
            float zz = (((t >> (7 - i)) ^ (t >> (6 - i))) & 1) ? -1.f : 1.f;
            ang = fmaf(w[l * 15 + 8 + i], zz, ang);
        }
        float sv, cv;
        __sincosf(0.5f * ang, &sv, &cv);
        v2f d; d.x = cv; d.y = -sv;        // exp(-0.5 i ang)
        s_diag[l][t] = d;
    }
    if (t < 24) {
        int l = t >> 3, q = t & 7;
        float a = 0.5f * w[l * 15 + q];
        v2f cs; cs.x = __cosf(a); cs.y = __sinf(a);
        s_cs[l][q] = cs;
    }
    __syncthreads();

    const int lane = t & 63;
    const int sub = ((lane >> 1) & 4) | (lane & 3);          // {b3,b1,b0}
    const int swv = ((lane >> 4) << 1) | ((lane >> 2) & 1);  // sample in wave
    const int s = blockIdx.x * 32 + ((t >> 6) << 3) + swv;
    if (s >= nsamp) return;

    // ---- per-wire single-qubit state after the layer-0 RY (product state)
    // |0> -> RY(asin z1) -> RZ(asin z2): v0 = cos(a1/2) e^{-i a2/2},
    //                                    v1 = sin(a1/2) e^{+i a2/2}
    const float z1v = z1[s], z2v = z2[s];
    const float u1 = sqrtf(fmaxf(0.f, 1.f - z1v * z1v));  // cos a1
    const float u2 = sqrtf(fmaxf(0.f, 1.f - z2v * z2v));  // cos a2
    const float c1 = sqrtf(0.5f * (1.f + u1));
    const float s1v = copysignf(sqrtf(fmaxf(0.f, 0.5f * (1.f - u1))), z1v);
    const float ch = sqrtf(0.5f * (1.f + u2));
    const float sh = copysignf(sqrtf(fmaxf(0.f, 0.5f * (1.f - u2))), z2v);
    v2f v0; v0.x = c1 * ch;  v0.y = -c1 * sh;
    v2f v1; v1.x = s1v * ch; v1.y = s1v * sh;

    // Apply layer-0 RY(w[0][q]) per wire: A=alpha (bit=0), Bt=beta (bit=1)
    v2f A[8], Bt[8];
    #pragma unroll
    for (int q = 0; q < 8; ++q) {
        const v2f cs = s_cs[0][q];
        A[q]  = splat(cs.x) * v0 - splat(cs.y) * v1;
        Bt[q] = splat(cs.y) * v0 + splat(cs.x) * v1;
    }

    // Lane-wire factor (wires 5,6,7 <-> lane bits 3,1,0), then product tree
    // over register wires 4..0 (i bit k <-> wire 4-k).
    v2f amp[32];
    amp[0] = cmul((lane & 8) ? Bt[5] : A[5],
                  cmul((lane & 2) ? Bt[6] : A[6], (lane & 1) ? Bt[7] : A[7]));
    #pragma unroll
    for (int k = 0; k < 5; ++k) {
        const v2f Aq = A[4 - k], Bq = Bt[4 - k];
        #pragma unroll
        for (int j = 0; j < (1 << k); ++j) {
            amp[j | (1 << k)] = cmul(amp[j], Bq);
            amp[j]            = cmul(amp[j], Aq);
        }
    }

    // ---- entangler diag 0, RY layer 1, diag 1, RY layer 2
    #pragma unroll
    for (int i = 0; i < 32; ++i)
        amp[i] = cmul(amp[i], s_diag[0][(i << 3) | sub]);

    #pragma unroll
    for (int l = 1; l < 3; ++l) {
        // register wires 0..4 (i bit 4-q)
        #pragma unroll
        for (int q = 0; q < 5; ++q) {
            const int b = 4 - q;
            const v2f cs = s_cs[l][q];
            const v2f cq = splat(cs.x), sq = splat(cs.y);
            #pragma unroll
            for (int h = 0; h < 16; ++h) {
                const int lm = (1 << b) - 1;
                const int i0 = ((h & ~lm) << 1) | (h & lm);
                const int i1 = i0 | (1 << b);
                const v2f a0 = amp[i0], a1 = amp[i1];
                amp[i0] = cq * a0 - sq * a1;
                amp[i1] = sq * a0 + cq * a1;
            }
        }
        // wire 5: lane xor 8 (row_ror:8)
        {
            const v2f cs = s_cs[l][5];
            const v2f cq = splat(cs.x);
            const v2f se = splat((lane & 8) ? cs.y : -cs.y);
            #pragma unroll
            for (int i = 0; i < 32; ++i)
                amp[i] = cq * amp[i] + se * dpp2<DPP_XOR8>(amp[i]);
        }
        // wire 6: lane xor 2
        {
            const v2f cs = s_cs[l][6];
            const v2f cq = splat(cs.x);
            const v2f se = splat((lane & 2) ? cs.y : -cs.y);
            #pragma unroll
            for (int i = 0; i < 32; ++i)
                amp[i] = cq * amp[i] + se * dpp2<DPP_XOR2>(amp[i]);
        }
        // wire 7: lane xor 1
        {
            const v2f cs = s_cs[l][7];
            const v2f cq = splat(cs.x);
            const v2f se = splat((lane & 1) ? cs.y : -cs.y);
            #pragma unroll
            for (int i = 0; i < 32; ++i)
                amp[i] = cq * amp[i] + se * dpp2<DPP_XOR1>(amp[i]);
        }
        if (l == 1) {
            #pragma unroll
            for (int i = 0; i < 32; ++i)
                amp[i] = cmul(amp[i], s_diag[1][(i << 3) | sub]);
        }
        // l==2: diag is a pure phase before |.|^2 -> skip
    }

    // ---- probabilities + signed sums
    float pr[32];
    #pragma unroll
    for (int i = 0; i < 32; ++i)
        pr[i] = fmaf(amp[i].x, amp[i].x, amp[i].y * amp[i].y);

    float S[8];
    #pragma unroll
    for (int q = 0; q < 5; ++q) {        // register wires, MSB-first peel
        const int half = 16 >> q;
        float d = 0.f;
        #pragma unroll
        for (int j = 0; j < half; ++j) {
            d += pr[j] - pr[j + half];
            pr[j] += pr[j + half];
        }
        S[q] = d;
    }
    const float T = pr[0];               // lane-local probability mass
    S[5] = (lane & 8) ? -T : T;
    S[6] = (lane & 2) ? -T : T;
    S[7] = (lane & 1) ? -T : T;

    // butterfly over the sample's 8 lanes (bits 0,1,3; bit 2 = sample select)
    #pragma unroll
    for (int k = 0; k < 8; ++k) {
        S[k] += dppf<DPP_XOR1>(S[k]);
        S[k] += dppf<DPP_XOR2>(S[k]);
        S[k] += dppf<DPP_XOR8>(S[k]);
    }

    // lane with sub value r writes out[s*8+r] = S[r]; wave covers 256B contig
    float a01 = (lane & 1) ? S[1] : S[0];
    float a23 = (lane & 1) ? S[3] : S[2];
    float a45 = (lane & 1) ? S[5] : S[4];
    float a67 = (lane & 1) ? S[7] : S[6];
    float b03 = (lane & 2) ? a23 : a01;
    float b47 = (lane & 2) ? a67 : a45;
    out[(size_t)s * 8 + sub] = (lane & 8) ? b47 : b03;
}

extern "C" void kernel_launch(void* const* d_in, const int* in_sizes, int n_in,
                              void* d_out, int out_size, void* d_ws,
                              size_t ws_size, hipStream_t stream) {
    const float* w  = (const float*)d_in[0];   // (3, 15) f32
    const float* z1 = (const float*)d_in[1];   // (B,)   f32
    const float* z2 = (const float*)d_in[2];   // (B,)   f32
    float* out = (float*)d_out;                // (B, 8) f32

    const int n = in_sizes[1];
    const int blocks = (n * 8 + 255) / 256;
    qsim_kernel<<<blocks, 256, 0, stream>>>(w, z1, z2, out, n);
}